// Round 7
// baseline (135.929 us; speedup 1.0000x reference)
//
#include <hip/hip_runtime.h>

#define NUM_NODES 10000
#define TSTEPS 1440
#define VCOLS 360          // 1440/4 float4 columns
#define PVC 388            // padded f4 row stride (6208 B, odd 256B multiple)
#define NPART 1000         // one partial row per block
#define ROWS_PER_BLOCK 10  // 1000 * 10 = 10000 rows exactly
#define PH2_BLOCKS 90      // blocks 0..89 do phase 2 (4 f4-cols each)

__device__ __forceinline__ void f4add(float4& a, const float4 b) {
    a.x += b.x; a.y += b.y; a.z += b.z; a.w += b.w;
}

// Fused single kernel with a MANUAL spin barrier (round-6 lesson:
// hipLaunchCooperativeKernel fails in this harness — output never written).
// Deadlock-safety by capacity: __launch_bounds__(256,8) caps VGPR at 64 ->
// 8 blocks/CU -> 2048 co-residency capacity >> 1000-block grid, so every
// block is dispatched regardless of others spinning. Counter is zeroed by a
// 4-byte hipMemsetAsync node each call (ws is poisoned 0xAA and never
// re-poisoned, so the kernel cannot assume any initial counter value).
// Cross-XCD visibility of partials: __threadfence() release before the
// device-scope atomicAdd, __threadfence() acquire after the spin (per-XCD
// L2s are not coherent without device-scope ops).
__global__ __launch_bounds__(256, 8) void fused_kernel(
        const float* __restrict__ noise,
        float4* __restrict__ part,
        int* __restrict__ counter,
        const float* __restrict__ time_tensor,
        float* __restrict__ out) {
    int tid = threadIdx.x;           // 0..255
    int b   = blockIdx.x;            // 0..999

    // ---- Phase 1: block b sums rows [10b, 10b+10) -> part[b][0..359] ----
    const float4* base = (const float4*)noise + (size_t)b * ROWS_PER_BLOCK * VCOLS;
    #pragma unroll
    for (int pass = 0; pass < 2; ++pass) {
        int c = tid + pass * 256;
        if (c < VCOLS) {
            const float4* p = base + c;
            float4 v0 = p[0 * VCOLS], v1 = p[1 * VCOLS], v2 = p[2 * VCOLS],
                   v3 = p[3 * VCOLS], v4 = p[4 * VCOLS];
            float4 acc = v0;
            f4add(acc, v1); f4add(acc, v2); f4add(acc, v3); f4add(acc, v4);
            v0 = p[5 * VCOLS]; v1 = p[6 * VCOLS]; v2 = p[7 * VCOLS];
            v3 = p[8 * VCOLS]; v4 = p[9 * VCOLS];
            f4add(acc, v0); f4add(acc, v1); f4add(acc, v2);
            f4add(acc, v3); f4add(acc, v4);
            part[(size_t)b * PVC + c] = acc;
        }
    }

    // ---- Grid barrier (arrive + spin; bounded so a bug can't hang) ----
    __syncthreads();
    if (tid == 0) {
        __threadfence();                         // release partial stores
        atomicAdd(counter, 1);                   // device-scope (m20)
        long spin = 0;
        while (__hip_atomic_load(counter, __ATOMIC_RELAXED,
                                 __HIP_MEMORY_SCOPE_AGENT) < NPART) {
            __builtin_amdgcn_s_sleep(4);
            if (++spin > 10000000L) break;       // bailout >> any legit wait
        }
        __threadfence();                         // acquire partials
    }
    __syncthreads();

    // ---- Phase 2: blocks 0..89 reduce 4 f4-cols of 1000 partials each ----
    if (b >= PH2_BLOCKS) return;
    int c4  = tid & 3;               // f4-col within block tile (0..3)
    int jr  = tid >> 2;              // 0..63
    int c4g = b * 4 + c4;            // global f4-col 0..359

    // 4 consecutive lanes read 64 consecutive bytes -> line-exact traffic.
    float4 a0 = make_float4(0.f, 0.f, 0.f, 0.f), a1 = a0;
    const float4* q = part + c4g;
    #pragma unroll
    for (int k = 0; k < 7; ++k) {    // j = jr + 64*(2k), jr + 64*(2k+1): j<=959
        float4 u0 = q[(size_t)(jr + 128 * k) * PVC];
        float4 u1 = q[(size_t)(jr + 128 * k + 64) * PVC];
        f4add(a0, u0); f4add(a1, u1);
    }
    {                                 // k=7: j = jr+896 (<1000), jr+960 (<1000 iff jr<40)
        float4 u0 = q[(size_t)(jr + 896) * PVC];
        f4add(a0, u0);
        if (jr < NPART - 960) {
            float4 u1 = q[(size_t)(jr + 960) * PVC];
            f4add(a1, u1);
        }
    }
    f4add(a0, a1);

    __shared__ float4 red[64][4];
    red[jr][c4] = a0;
    __syncthreads();

    if (tid < 64) {                  // wave 0: c4 = tid&3, jrs = tid>>2 (0..15)
        int jrs = tid >> 2, cc = tid & 3;
        float4 s = red[jrs][cc];
        f4add(s, red[jrs + 16][cc]);
        f4add(s, red[jrs + 32][cc]);
        f4add(s, red[jrs + 48][cc]);
        #pragma unroll
        for (int off = 32; off >= 4; off >>= 1) {
            s.x += __shfl_down(s.x, off, 64);
            s.y += __shfl_down(s.y, off, 64);
            s.z += __shfl_down(s.z, off, 64);
            s.w += __shfl_down(s.w, off, 64);
        }
        if (tid < 4) {               // lane l holds f4-col b*4 + l
            int cg = b * 4 + tid;
            // overall[t] = 0.8*colmean + 0.5 + 0.3*sin(2pi*(10/3600)*time[t])
            //   (mean over nodes of sin(theta_t + i*2pi/N) is exactly 0:
            //    equally spaced phases -> sum of N-th roots of unity = 0)
            // encrypted[t] = sin(0.5*overall[t])
            const float TWO_PI = 6.2831853071795864769f;
            const float BWF = 10.0f / 3600.0f;
            const float INV_N = 1.0f / NUM_NODES;
            float4 tm = ((const float4*)time_tensor)[cg];
            float4 ov, en;
            ov.x = 0.8f * (s.x * INV_N) + 0.5f + 0.3f * sinf(TWO_PI * BWF * tm.x);
            ov.y = 0.8f * (s.y * INV_N) + 0.5f + 0.3f * sinf(TWO_PI * BWF * tm.y);
            ov.z = 0.8f * (s.z * INV_N) + 0.5f + 0.3f * sinf(TWO_PI * BWF * tm.z);
            ov.w = 0.8f * (s.w * INV_N) + 0.5f + 0.3f * sinf(TWO_PI * BWF * tm.w);
            en.x = sinf(0.5f * ov.x);
            en.y = sinf(0.5f * ov.y);
            en.z = sinf(0.5f * ov.z);
            en.w = sinf(0.5f * ov.w);
            ((float4*)out)[TSTEPS / 4 + cg] = ov;   // overall   [1440, 2880)
            ((float4*)out)[cg] = en;                // encrypted [0, 1440)
        }
    }
}

extern "C" void kernel_launch(void* const* d_in, const int* in_sizes, int n_in,
                              void* d_out, int out_size, void* d_ws, size_t ws_size,
                              hipStream_t stream) {
    const float* time_tensor = (const float*)d_in[0];   // [1440]
    const float* noise       = (const float*)d_in[1];   // [10000, 1440]
    float* out   = (float*)d_out;                       // [2880]
    int*   counter = (int*)d_ws;                        // 4 B at ws offset 0
    float4* part = (float4*)((char*)d_ws + 256);        // 1000*388 f4 = 6.2 MB

    hipMemsetAsync(counter, 0, sizeof(int), stream);    // graph-legal init
    fused_kernel<<<NPART, 256, 0, stream>>>(noise, part, counter,
                                            time_tensor, out);
}

// Round 8
// 67.372 us; speedup vs baseline: 2.0176x; 2.0176x over previous
//
#include <hip/hip_runtime.h>

#define NUM_NODES 10000
#define TSTEPS 1440
#define VCOLS 360          // 1440/4 float4 columns
#define PVC 388            // padded f4 row stride (6208 B, odd 256B multiple)
#define NPART 1000         // one partial row per block
#define RPB 10             // rows per block: 1000 * 10 = 10000
#define PH2_BLOCKS 90      // blocks 0..89 do phase 2 (4 f4-cols each)

__device__ __forceinline__ void f4add(float4& a, const float4 b) {
    a.x += b.x; a.y += b.y; a.z += b.z; a.w += b.w;
}

// Fused kernel, FLAG-ARRAY grid barrier.
// Round-7 lesson (measured): same-address device atomic RMW = ~136 ns
// serialized; a 1000-arrival single-counter barrier = 136 us. This version
// has ZERO atomic RMWs: each block release-stores its own flags[b] (1000
// distinct addresses, fully parallel); only the 90 phase-2 blocks poll.
// Blocks 90..999 exit immediately after signaling -> no residency demand;
// capacity is ample anyway (<=64 VGPR via __launch_bounds__(256,8) -> 8
// blocks/CU -> 2048 slots >= 1000).
// Cross-XCD visibility: __syncthreads() drains the block's partial stores
// (compiler emits s_waitcnt vmcnt(0) before s_barrier), then tid0 does an
// agent-scope release (__threadfence + release store); readers acquire.
__global__ __launch_bounds__(256, 8) void fused_kernel(
        const float* __restrict__ noise,
        float4* __restrict__ part,
        int* __restrict__ flags,
        const float* __restrict__ time_tensor,
        float* __restrict__ out) {
    int tid = threadIdx.x;           // 0..255
    int b   = blockIdx.x;            // 0..999

    // ---- Phase 1: block b sums rows [10b, 10b+10) -> part[b][0..359] ----
    const float4* base = (const float4*)noise + (size_t)b * RPB * VCOLS;
    #pragma unroll
    for (int pass = 0; pass < 2; ++pass) {
        int c = tid + pass * 256;
        if (c < VCOLS) {
            const float4* p = base + c;
            float4 v0 = p[0 * VCOLS], v1 = p[1 * VCOLS], v2 = p[2 * VCOLS],
                   v3 = p[3 * VCOLS], v4 = p[4 * VCOLS];
            float4 w0 = p[5 * VCOLS], w1 = p[6 * VCOLS], w2 = p[7 * VCOLS],
                   w3 = p[8 * VCOLS], w4 = p[9 * VCOLS];
            f4add(v0, v1); f4add(v2, v3); f4add(w0, w1); f4add(w2, w3);
            f4add(v0, v2); f4add(w0, w2);
            f4add(v0, v4); f4add(w0, w4);
            f4add(v0, w0);
            part[(size_t)b * PVC + c] = v0;
        }
    }

    // ---- Arrival: one plain release store per block (no RMW) ----
    __syncthreads();                               // drain partial stores
    if (tid == 0) {
        __threadfence();                           // agent release fence
        __hip_atomic_store(&flags[b], 1, __ATOMIC_RELEASE,
                           __HIP_MEMORY_SCOPE_AGENT);
    }
    if (b >= PH2_BLOCKS) return;                   // producers done

    // ---- Wait: 256 threads poll 1000 distinct flags cooperatively ----
    __shared__ int not_done;
    int rounds = 0;
    for (;;) {
        if (tid == 0) not_done = 0;
        __syncthreads();
        int miss = 0;
        for (int f = tid; f < NPART; f += 256)     // 4 loads/thread/round
            miss |= (__hip_atomic_load(&flags[f], __ATOMIC_RELAXED,
                                       __HIP_MEMORY_SCOPE_AGENT) == 0);
        if (miss) not_done = 1;                    // benign block-local race
        __syncthreads();
        if (!not_done) break;
        if (++rounds > 100000) break;              // safety: never hang
    }
    __threadfence();                               // acquire partials

    // ---- Phase 2: block b reduces f4-cols [4b, 4b+4) over 1000 partials ----
    int c4  = tid & 3;               // f4-col within tile (0..3)
    int jr  = tid >> 2;              // 0..63
    int c4g = b * 4 + c4;            // global f4-col 0..359

    float4 a0 = make_float4(0.f, 0.f, 0.f, 0.f), a1 = a0;
    const float4* q = part + c4g;
    #pragma unroll
    for (int k = 0; k < 7; ++k) {    // j = jr+128k, jr+128k+64  (max 895)
        float4 u0 = q[(size_t)(jr + 128 * k) * PVC];
        float4 u1 = q[(size_t)(jr + 128 * k + 64) * PVC];
        f4add(a0, u0); f4add(a1, u1);
    }
    {                                // tail: j = jr+896; j = jr+960 if jr<40
        float4 u0 = q[(size_t)(jr + 896) * PVC];
        f4add(a0, u0);
        if (jr < NPART - 960) {
            float4 u1 = q[(size_t)(jr + 960) * PVC];
            f4add(a1, u1);
        }
    }
    f4add(a0, a1);

    __shared__ float4 red[64][4];
    red[jr][c4] = a0;
    __syncthreads();

    if (tid < 64) {                  // wave 0: jrs = tid>>2 (0..15), cc = tid&3
        int jrs = tid >> 2, cc = tid & 3;
        float4 s = red[jrs][cc];
        f4add(s, red[jrs + 16][cc]);
        f4add(s, red[jrs + 32][cc]);
        f4add(s, red[jrs + 48][cc]);
        #pragma unroll
        for (int off = 32; off >= 4; off >>= 1) {
            s.x += __shfl_down(s.x, off, 64);
            s.y += __shfl_down(s.y, off, 64);
            s.z += __shfl_down(s.z, off, 64);
            s.w += __shfl_down(s.w, off, 64);
        }
        if (tid < 4) {               // lane l holds f4-col b*4 + l
            int cg = b * 4 + tid;
            // overall[t] = 0.8*colmean + 0.5 + 0.3*sin(2pi*(10/3600)*time[t])
            //   (mean over nodes of sin(theta_t + i*2pi/N) is exactly 0:
            //    equally spaced phases -> sum of N-th roots of unity = 0)
            // encrypted[t] = sin(0.5*overall[t])
            const float TWO_PI = 6.2831853071795864769f;
            const float BWF = 10.0f / 3600.0f;
            const float INV_N = 1.0f / NUM_NODES;
            float4 tm = ((const float4*)time_tensor)[cg];
            float4 ov, en;
            ov.x = 0.8f * (s.x * INV_N) + 0.5f + 0.3f * sinf(TWO_PI * BWF * tm.x);
            ov.y = 0.8f * (s.y * INV_N) + 0.5f + 0.3f * sinf(TWO_PI * BWF * tm.y);
            ov.z = 0.8f * (s.z * INV_N) + 0.5f + 0.3f * sinf(TWO_PI * BWF * tm.z);
            ov.w = 0.8f * (s.w * INV_N) + 0.5f + 0.3f * sinf(TWO_PI * BWF * tm.w);
            en.x = sinf(0.5f * ov.x);
            en.y = sinf(0.5f * ov.y);
            en.z = sinf(0.5f * ov.z);
            en.w = sinf(0.5f * ov.w);
            ((float4*)out)[TSTEPS / 4 + cg] = ov;   // overall   [1440, 2880)
            ((float4*)out)[cg] = en;                // encrypted [0, 1440)
        }
    }
}

extern "C" void kernel_launch(void* const* d_in, const int* in_sizes, int n_in,
                              void* d_out, int out_size, void* d_ws, size_t ws_size,
                              hipStream_t stream) {
    const float* time_tensor = (const float*)d_in[0];   // [1440]
    const float* noise       = (const float*)d_in[1];   // [10000, 1440]
    float* out   = (float*)d_out;                       // [2880]
    int*   flags = (int*)d_ws;                          // 1000 ints at offset 0
    float4* part = (float4*)((char*)d_ws + 8192);       // 1000*388 f4 = 6.2 MB

    hipMemsetAsync(flags, 0, NPART * sizeof(int), stream);  // graph-legal
    fused_kernel<<<NPART, 256, 0, stream>>>(noise, part, flags,
                                            time_tensor, out);
}

// Round 9
// 17.511 us; speedup vs baseline: 7.7626x; 3.8475x over previous
//
#include <hip/hip_runtime.h>

#define NUM_NODES 10000
#define TSTEPS 1440
#define VCOLS 360          // 1440/4 float4 columns
#define PVC 364            // padded f4 row stride: 5824 B = 91 cache lines
                           // (odd multiple -> consecutive rows spread L2 channels)
#define NPART 250          // partial rows (one per stage-1 block)
#define RPB 40             // rows per block: 250 * 40 = 10000 exactly

__device__ __forceinline__ void f4add(float4& a, const float4 b) {
    a.x += b.x; a.y += b.y; a.z += b.z; a.w += b.w;
}

// TWO-KERNEL structure, by measurement:
//  - round 7: graph/dispatch overhead is ~0.25 us -> fusion saves nothing real
//  - round 7: same-address atomic RMW = ~136 ns serialized (counter barrier = 136 us)
//  - round 8: per-block agent release (L2 writeback) ~ 0.5 us x 1000 blocks = 67 us
// The kernel boundary is the only cheap grid-wide barrier on this chip.

// Stage 1: block b sums rows [40b, 40b+40) -> part[b][0..359].
// 250 blocks x 6 waves, 8 independent float4 loads in flight per thread
// (11.5 MB in flight >> ~6 MB BW*latency product) -> HBM-saturating.
// Tree-add per 8-batch keeps the acc dependence chain at 1 add/iteration.
__global__ __launch_bounds__(384, 4) void partial_sum_kernel(
        const float* __restrict__ noise, float4* __restrict__ part) {
    int vc = threadIdx.x;            // 0..383 (384..: idle, 6% waste)
    int b  = blockIdx.x;             // 0..249
    if (vc < VCOLS) {
        const float4* p = (const float4*)noise + (size_t)b * RPB * VCOLS + vc;
        float4 acc = make_float4(0.f, 0.f, 0.f, 0.f);
        #pragma unroll 1             // keep 8 loads in flight, ~40 VGPR
        for (int it = 0; it < RPB / 8; ++it) {
            float4 v0 = p[0 * VCOLS], v1 = p[1 * VCOLS];
            float4 v2 = p[2 * VCOLS], v3 = p[3 * VCOLS];
            float4 v4 = p[4 * VCOLS], v5 = p[5 * VCOLS];
            float4 v6 = p[6 * VCOLS], v7 = p[7 * VCOLS];
            p += 8 * VCOLS;
            f4add(v0, v1); f4add(v2, v3); f4add(v4, v5); f4add(v6, v7);
            f4add(v0, v2); f4add(v4, v6);
            f4add(v0, v4);
            f4add(acc, v0);
        }
        part[(size_t)b * PVC + vc] = acc;
    }
}

// Stage 2: 90 blocks x 256 threads; thread (c4 = tid&3, jr = tid>>2) reads
// rows j = jr, jr+64, jr+128 (+ jr+192 if jr<58) of its f4-column.
// 4 consecutive lanes cover one 64 B line -> line-exact 1.46 MB, all L2/L3.
// Then LDS tree 64->16, wave-0 shuffle 16->1, lanes 0-3 fused finalize:
// overall[t] = 0.8*colmean + 0.5 + 0.3*sin(2pi*(10/3600)*time[t])
//   (mean over nodes of sin(theta_t + i*2pi/N) is exactly 0: equally spaced
//    phases over a full circle -> sum of N-th roots of unity = 0)
// encrypted[t] = sin(0.5*overall[t]); out = [encrypted(1440) | overall(1440)]
__global__ __launch_bounds__(256, 4) void reduce_finalize_kernel(
        const float* __restrict__ time_tensor,
        const float4* __restrict__ part,
        float* __restrict__ out) {
    int tid = threadIdx.x;
    int c4  = tid & 3;               // f4-col within tile (0..3)
    int jr  = tid >> 2;              // 0..63
    int c4g = blockIdx.x * 4 + c4;   // global f4-col 0..359

    const float4* q = part + c4g;
    float4 a0 = q[(size_t)jr * PVC];
    float4 b0 = q[(size_t)(jr + 64) * PVC];
    float4 c0 = q[(size_t)(jr + 128) * PVC];
    f4add(a0, c0);
    if (jr < NPART - 192)            // j = jr+192 <= 249
        f4add(b0, q[(size_t)(jr + 192) * PVC]);
    f4add(a0, b0);

    __shared__ float4 red[64][4];
    red[jr][c4] = a0;
    __syncthreads();

    if (tid < 64) {                  // wave 0: jrs = tid>>2 (0..15), cc = tid&3
        int jrs = tid >> 2, cc = tid & 3;
        float4 s = red[jrs][cc];
        f4add(s, red[jrs + 16][cc]);
        f4add(s, red[jrs + 32][cc]);
        f4add(s, red[jrs + 48][cc]);
        #pragma unroll
        for (int off = 32; off >= 4; off >>= 1) {
            s.x += __shfl_down(s.x, off, 64);
            s.y += __shfl_down(s.y, off, 64);
            s.z += __shfl_down(s.z, off, 64);
            s.w += __shfl_down(s.w, off, 64);
        }
        if (tid < 4) {               // lane l holds f4-col blockIdx*4 + l
            int cg = blockIdx.x * 4 + tid;
            const float TWO_PI = 6.2831853071795864769f;
            const float BWF = 10.0f / 3600.0f;
            const float INV_N = 1.0f / NUM_NODES;
            float4 tm = ((const float4*)time_tensor)[cg];
            float4 ov, en;
            ov.x = 0.8f * (s.x * INV_N) + 0.5f + 0.3f * sinf(TWO_PI * BWF * tm.x);
            ov.y = 0.8f * (s.y * INV_N) + 0.5f + 0.3f * sinf(TWO_PI * BWF * tm.y);
            ov.z = 0.8f * (s.z * INV_N) + 0.5f + 0.3f * sinf(TWO_PI * BWF * tm.z);
            ov.w = 0.8f * (s.w * INV_N) + 0.5f + 0.3f * sinf(TWO_PI * BWF * tm.w);
            en.x = sinf(0.5f * ov.x);
            en.y = sinf(0.5f * ov.y);
            en.z = sinf(0.5f * ov.z);
            en.w = sinf(0.5f * ov.w);
            ((float4*)out)[TSTEPS / 4 + cg] = ov;   // overall   [1440, 2880)
            ((float4*)out)[cg] = en;                // encrypted [0, 1440)
        }
    }
}

extern "C" void kernel_launch(void* const* d_in, const int* in_sizes, int n_in,
                              void* d_out, int out_size, void* d_ws, size_t ws_size,
                              hipStream_t stream) {
    const float* time_tensor = (const float*)d_in[0];   // [1440]
    const float* noise       = (const float*)d_in[1];   // [10000, 1440]
    float* out   = (float*)d_out;                       // [2880]
    float4* part = (float4*)d_ws;                       // 250*364 f4 = 1.46 MB

    partial_sum_kernel<<<NPART, 384, 0, stream>>>(noise, part);
    reduce_finalize_kernel<<<VCOLS / 4, 256, 0, stream>>>(time_tensor, part, out);
}